// Round 3
// baseline (215.915 us; speedup 1.0000x reference)
//
#include <hip/hip_runtime.h>
#include <hip/hip_bf16.h>

#define BLOCK 256
#define GRID 2048

typedef float floatx4 __attribute__((ext_vector_type(4)));
typedef int   intx4   __attribute__((ext_vector_type(4)));

__device__ __forceinline__ float row_loss(floatx4 x, int t, const float* sw) {
    // argmax, first-occurrence tie-break (strictly-greater scan)
    float best = x.x; int pred = 0;
    if (x.y > best) { best = x.y; pred = 1; }
    if (x.z > best) { best = x.z; pred = 2; }
    if (x.w > best) { best = x.w; pred = 3; }
    const float sev = sw[t * 4 + pred];
    // native-rate transcendentals: v_exp_f32 / v_log_f32
    const float s = __expf(x.x - best) + __expf(x.y - best) +
                    __expf(x.z - best) + __expf(x.w - best);
    const float lse = best + __logf(s);
    const float xt = (t == 0) ? x.x : (t == 1) ? x.y : (t == 2) ? x.z : x.w;
    return sev + (lse - xt);
}

__global__ __launch_bounds__(BLOCK) void wcl_main_kernel(
    const floatx4* __restrict__ out4,     // [B] rows of 4 logits
    const intx4*   __restrict__ tgt4,     // [B/4] targets, 4 per load
    const float*   __restrict__ w,        // [16] severity weights
    float*         __restrict__ partials, // [GRID] per-block sums
    int ngroups)                          // B/4
{
    __shared__ float sw[16];
    __shared__ float wave_sums[BLOCK / 64];

    if (threadIdx.x < 16) sw[threadIdx.x] = w[threadIdx.x];
    __syncthreads();

    const int stride = GRID * BLOCK;
    int g = blockIdx.x * BLOCK + threadIdx.x;

    float local = 0.0f;
    // 2 groups (8 rows) per pass: 10 independent loads (160 B) in flight
    for (; g + stride < ngroups; g += 2 * stride) {
        const int g1 = g + stride;
        intx4 t0 = __builtin_nontemporal_load(&tgt4[g]);
        intx4 t1 = __builtin_nontemporal_load(&tgt4[g1]);
        floatx4 a0 = __builtin_nontemporal_load(&out4[4 * g + 0]);
        floatx4 a1 = __builtin_nontemporal_load(&out4[4 * g + 1]);
        floatx4 a2 = __builtin_nontemporal_load(&out4[4 * g + 2]);
        floatx4 a3 = __builtin_nontemporal_load(&out4[4 * g + 3]);
        floatx4 b0 = __builtin_nontemporal_load(&out4[4 * g1 + 0]);
        floatx4 b1 = __builtin_nontemporal_load(&out4[4 * g1 + 1]);
        floatx4 b2 = __builtin_nontemporal_load(&out4[4 * g1 + 2]);
        floatx4 b3 = __builtin_nontemporal_load(&out4[4 * g1 + 3]);
        local += row_loss(a0, t0.x, sw);
        local += row_loss(a1, t0.y, sw);
        local += row_loss(a2, t0.z, sw);
        local += row_loss(a3, t0.w, sw);
        local += row_loss(b0, t1.x, sw);
        local += row_loss(b1, t1.y, sw);
        local += row_loss(b2, t1.z, sw);
        local += row_loss(b3, t1.w, sw);
    }
    for (; g < ngroups; g += stride) {
        intx4 t = __builtin_nontemporal_load(&tgt4[g]);
        floatx4 a0 = __builtin_nontemporal_load(&out4[4 * g + 0]);
        floatx4 a1 = __builtin_nontemporal_load(&out4[4 * g + 1]);
        floatx4 a2 = __builtin_nontemporal_load(&out4[4 * g + 2]);
        floatx4 a3 = __builtin_nontemporal_load(&out4[4 * g + 3]);
        local += row_loss(a0, t.x, sw);
        local += row_loss(a1, t.y, sw);
        local += row_loss(a2, t.z, sw);
        local += row_loss(a3, t.w, sw);
    }

    // wave-64 shuffle reduction
    #pragma unroll
    for (int off = 32; off > 0; off >>= 1)
        local += __shfl_down(local, off);

    const int lane = threadIdx.x & 63;
    const int wave = threadIdx.x >> 6;
    if (lane == 0) wave_sums[wave] = local;
    __syncthreads();

    if (threadIdx.x == 0) {
        float bsum = 0.0f;
        #pragma unroll
        for (int j = 0; j < BLOCK / 64; ++j) bsum += wave_sums[j];
        partials[blockIdx.x] = bsum;
    }
}

__global__ __launch_bounds__(BLOCK) void wcl_final_kernel(
    const float* __restrict__ partials, float* __restrict__ out, int B)
{
    __shared__ double wave_sums[BLOCK / 64];
    double local = 0.0;
    for (int i = threadIdx.x; i < GRID; i += BLOCK)
        local += (double)partials[i];

    #pragma unroll
    for (int off = 32; off > 0; off >>= 1)
        local += __shfl_down(local, off);

    const int lane = threadIdx.x & 63;
    const int wave = threadIdx.x >> 6;
    if (lane == 0) wave_sums[wave] = local;
    __syncthreads();

    if (threadIdx.x == 0) {
        double s = 0.0;
        #pragma unroll
        for (int j = 0; j < BLOCK / 64; ++j) s += wave_sums[j];
        out[0] = (float)(s / (double)B);
    }
}

extern "C" void kernel_launch(void* const* d_in, const int* in_sizes, int n_in,
                              void* d_out, int out_size, void* d_ws, size_t ws_size,
                              hipStream_t stream) {
    const float* outputs = (const float*)d_in[0];   // [B,4] fp32
    const int*   targets = (const int*)d_in[1];     // [B] int32
    const float* weights = (const float*)d_in[2];   // [4,4] fp32
    const int B = in_sizes[0] / 4;

    float* partials = (float*)d_ws;                 // GRID floats

    wcl_main_kernel<<<GRID, BLOCK, 0, stream>>>(
        (const floatx4*)outputs, (const intx4*)targets, weights, partials, B / 4);
    wcl_final_kernel<<<1, BLOCK, 0, stream>>>(partials, (float*)d_out, B);
}

// Round 4
// 204.473 us; speedup vs baseline: 1.0560x; 1.0560x over previous
//
#include <hip/hip_runtime.h>
#include <hip/hip_bf16.h>

#define BLOCK 256
#define GRID 2048

typedef float floatx4 __attribute__((ext_vector_type(4)));

__device__ __forceinline__ float row_loss(floatx4 x, int t, const float* sw) {
    // argmax, first-occurrence tie-break (strictly-greater scan)
    float best = x.x; int pred = 0;
    if (x.y > best) { best = x.y; pred = 1; }
    if (x.z > best) { best = x.z; pred = 2; }
    if (x.w > best) { best = x.w; pred = 3; }
    const float sev = sw[t * 4 + pred];
    // native-rate transcendentals: v_exp_f32 / v_log_f32
    const float s = __expf(x.x - best) + __expf(x.y - best) +
                    __expf(x.z - best) + __expf(x.w - best);
    const float lse = best + __logf(s);
    const float xt = (t == 0) ? x.x : (t == 1) ? x.y : (t == 2) ? x.z : x.w;
    return sev + (lse - xt);
}

__global__ __launch_bounds__(BLOCK) void wcl_main_kernel(
    const floatx4* __restrict__ out4,     // [B] rows of 4 logits
    const int*     __restrict__ tgt,      // [B] targets (0..3)
    const float*   __restrict__ w,        // [16] severity weights
    float*         __restrict__ partials, // [GRID] per-block sums
    int B)
{
    __shared__ float sw[16];
    __shared__ float wave_sums[BLOCK / 64];

    if (threadIdx.x < 16) sw[threadIdx.x] = w[threadIdx.x];
    __syncthreads();

    const int stride = GRID * BLOCK;
    int i = blockIdx.x * BLOCK + threadIdx.x;

    float local = 0.0f;
    // 4x unrolled grid-stride: every load instruction is lane-contiguous
    // (lane i -> out4[base+i], 1 KiB per wave per instruction)
    while (i + 3 * stride < B) {
        floatx4 x0 = __builtin_nontemporal_load(&out4[i]);
        floatx4 x1 = __builtin_nontemporal_load(&out4[i + stride]);
        floatx4 x2 = __builtin_nontemporal_load(&out4[i + 2 * stride]);
        floatx4 x3 = __builtin_nontemporal_load(&out4[i + 3 * stride]);
        int t0 = __builtin_nontemporal_load(&tgt[i]);
        int t1 = __builtin_nontemporal_load(&tgt[i + stride]);
        int t2 = __builtin_nontemporal_load(&tgt[i + 2 * stride]);
        int t3 = __builtin_nontemporal_load(&tgt[i + 3 * stride]);
        local += row_loss(x0, t0, sw);
        local += row_loss(x1, t1, sw);
        local += row_loss(x2, t2, sw);
        local += row_loss(x3, t3, sw);
        i += 4 * stride;
    }
    while (i < B) {
        floatx4 x = __builtin_nontemporal_load(&out4[i]);
        int t = __builtin_nontemporal_load(&tgt[i]);
        local += row_loss(x, t, sw);
        i += stride;
    }

    // wave-64 shuffle reduction
    #pragma unroll
    for (int off = 32; off > 0; off >>= 1)
        local += __shfl_down(local, off);

    const int lane = threadIdx.x & 63;
    const int wave = threadIdx.x >> 6;
    if (lane == 0) wave_sums[wave] = local;
    __syncthreads();

    if (threadIdx.x == 0) {
        float bsum = 0.0f;
        #pragma unroll
        for (int j = 0; j < BLOCK / 64; ++j) bsum += wave_sums[j];
        partials[blockIdx.x] = bsum;
    }
}

__global__ __launch_bounds__(BLOCK) void wcl_final_kernel(
    const float* __restrict__ partials, float* __restrict__ out, int B)
{
    __shared__ double wave_sums[BLOCK / 64];
    double local = 0.0;
    for (int i = threadIdx.x; i < GRID; i += BLOCK)
        local += (double)partials[i];

    #pragma unroll
    for (int off = 32; off > 0; off >>= 1)
        local += __shfl_down(local, off);

    const int lane = threadIdx.x & 63;
    const int wave = threadIdx.x >> 6;
    if (lane == 0) wave_sums[wave] = local;
    __syncthreads();

    if (threadIdx.x == 0) {
        double s = 0.0;
        #pragma unroll
        for (int j = 0; j < BLOCK / 64; ++j) s += wave_sums[j];
        out[0] = (float)(s / (double)B);
    }
}

extern "C" void kernel_launch(void* const* d_in, const int* in_sizes, int n_in,
                              void* d_out, int out_size, void* d_ws, size_t ws_size,
                              hipStream_t stream) {
    const float* outputs = (const float*)d_in[0];   // [B,4] fp32
    const int*   targets = (const int*)d_in[1];     // [B] int32
    const float* weights = (const float*)d_in[2];   // [4,4] fp32
    const int B = in_sizes[0] / 4;

    float* partials = (float*)d_ws;                 // GRID floats

    wcl_main_kernel<<<GRID, BLOCK, 0, stream>>>(
        (const floatx4*)outputs, targets, weights, partials, B);
    wcl_final_kernel<<<1, BLOCK, 0, stream>>>(partials, (float*)d_out, B);
}